// Round 11
// baseline (109.633 us; speedup 1.0000x reference)
//
#include <hip/hip_runtime.h>

#define NB 16384
#define TT 10
#define DIN 256
#define HH 16
#define NG 64      // 4*H
#define NF 160     // T*H
#define SPB 8      // samples per block (k_fused)
#define RPB 80     // rows per block
#define NBLK 2048  // NB/SPB

typedef __attribute__((ext_vector_type(8))) _Float16 half8;
typedef __attribute__((ext_vector_type(4))) _Float16 half4;
typedef __attribute__((ext_vector_type(4))) float f32x4;
typedef unsigned int u32;

__device__ __forceinline__ float rl_(float v, int l) {
    return __int_as_float(__builtin_amdgcn_readlane(__float_as_int(v), l));
}

// fire-and-forget 16B/lane global->LDS (lds dest: wave-uniform base + lane*16)
__device__ __forceinline__ void gld16(const float* g, float* l) {
    __builtin_amdgcn_global_load_lds(
        (const __attribute__((address_space(1))) u32*)g,
        (__attribute__((address_space(3))) u32*)l, 16, 0, 0);
}

// K0: one-time prep. B fragments (fp16, lane order) + fused layer-0 bias.
// lane l holds B[col=c*16+(l&15)][k=s*32+(l>>4)*8+j], at Bf[(c*8+s)*64+l].
__global__ __launch_bounds__(256) void k_prep(
        const float* __restrict__ w, const float* __restrict__ bi,
        const float* __restrict__ bh, half8* __restrict__ Bf,
        float* __restrict__ bsum) {
    const int fi = blockIdx.x * 256 + threadIdx.x;   // 0..2047
    const int c = fi >> 9;
    const int s = (fi >> 6) & 7;
    const int ll = fi & 63;
    const int row = c * 16 + (ll & 15);
    const int k0 = s * 32 + ((ll >> 4) << 3);
    const float* wp = w + (size_t)row * DIN + k0;
    float4 a = *(const float4*)wp;
    float4 b = *(const float4*)(wp + 4);
    half8 h;
    h[0] = (_Float16)a.x; h[1] = (_Float16)a.y;
    h[2] = (_Float16)a.z; h[3] = (_Float16)a.w;
    h[4] = (_Float16)b.x; h[5] = (_Float16)b.y;
    h[6] = (_Float16)b.z; h[7] = (_Float16)b.w;
    Bf[fi] = h;
    if (blockIdx.x == 0 && threadIdx.x < NG)
        bsum[threadIdx.x] = bi[threadIdx.x] + bh[threadIdx.x];
}

// K1: FUSED proj (f16 MFMA hi/lo, validated R6 stage/compute math) +
// 2-layer LSTM recurrence + flat store + BN partial sums.
// Block = 8 samples = 80 rows = 5 MFMA tiles over 4 waves (wave0 takes 2).
// B fragments in VGPRs; per-wave private 4KB LDS chunk staging (gld16),
// vmcnt(0)/lgkmcnt(0)+sched_barrier fences (R9 race discipline); xg stays
// in LDS (f16 fragment layout) — no global xg round-trip. One barrier.
__global__ __launch_bounds__(256, 2) void k_fused(
        const float* __restrict__ x, const half8* __restrict__ Bf,
        const float* __restrict__ bsum,
        const float* __restrict__ whh0, const float* __restrict__ wih1,
        const float* __restrict__ whh1, const float* __restrict__ bi1,
        const float* __restrict__ bh1,
        _Float16* __restrict__ flatH, float* __restrict__ psumT,
        float* __restrict__ psqT) {
    __shared__ float xs[4][1024];        // 16 KB: per-wave 16-row x 64-f32 chunk
    __shared__ _Float16 xg[5 * 4 * 64 * 4]; // 10 KB: (tile,c,lane,reg) f16
    __shared__ float ls2[SPB][NF];       // 5 KB: h1 history per sample

    const int tid = threadIdx.x;
    const int l = tid & 63;
    const int wv = tid >> 6;
    const int blk = blockIdx.x;
    const int row0b = blk * RPB;

    // B fragments -> VGPRs (32 x 1KB lane-contiguous loads, L2-hot)
    half8 breg[32];
    #pragma unroll
    for (int i = 0; i < 32; ++i) breg[i] = Bf[i * 64 + l];

    float* xbuf = &xs[wv][0];
    const int rr = l & 15;
    const int swzr = (rr & 7) << 4;

    // ---------------- phase A: projection (per-wave, barrier-free) --------
    for (int T = wv; T < 5; T += 4) {
        const int row0 = row0b + T * 16;
        f32x4 acc[4];
        #pragma unroll
        for (int c = 0; c < 4; ++c) acc[c] = (f32x4)0.0f;

        for (int kc = 0; kc < 4; ++kc) {
            // stage 16 rows x 256B (validated R6 geometry, swizzled source)
            #pragma unroll
            for (int p = 0; p < 4; ++p) {
                const int rloc = p * 4 + (l >> 4);
                const int cb = (kc << 8) + (((l & 15) << 4) ^ ((rloc & 7) << 4));
                gld16(x + (size_t)(row0 + rloc) * DIN + (cb >> 2), xbuf + p * 256);
            }
            asm volatile("s_waitcnt vmcnt(0)" ::: "memory");
            __builtin_amdgcn_sched_barrier(0);

            const char* rowp = (const char*)xbuf + rr * 256;
            #pragma unroll
            for (int sl = 0; sl < 2; ++sl) {
                const int s = kc * 2 + sl;
                const int b0 = sl * 128 + ((l >> 4) << 5);
                f32x4 va = *(const f32x4*)(rowp + (b0 ^ swzr));
                f32x4 vb = *(const f32x4*)(rowp + ((b0 + 16) ^ swzr));
                float fv[8] = {va.x, va.y, va.z, va.w, vb.x, vb.y, vb.z, vb.w};
                half8 ah, al;
                #pragma unroll
                for (int j = 0; j < 8; ++j) {
                    _Float16 hi = (_Float16)fv[j];
                    ah[j] = hi;
                    al[j] = (_Float16)(fv[j] - (float)hi);
                }
                #pragma unroll
                for (int c = 0; c < 4; ++c) {
                    acc[c] = __builtin_amdgcn_mfma_f32_16x16x32_f16(ah, breg[c * 8 + s], acc[c], 0, 0, 0);
                    acc[c] = __builtin_amdgcn_mfma_f32_16x16x32_f16(al, breg[c * 8 + s], acc[c], 0, 0, 0);
                }
            }
            asm volatile("s_waitcnt lgkmcnt(0)" ::: "memory");  // before buffer reuse
            __builtin_amdgcn_sched_barrier(0);
        }

        // acc -> xg LDS (f16, fragment layout; bias added in recurrence)
        #pragma unroll
        for (int c = 0; c < 4; ++c) {
            half4 hv;
            hv[0] = (_Float16)acc[c][0];
            hv[1] = (_Float16)acc[c][1];
            hv[2] = (_Float16)acc[c][2];
            hv[3] = (_Float16)acc[c][3];
            *(half4*)(xg + (((T * 4 + c) * 64 + l) << 2)) = hv;
        }
    }
    __syncthreads();

    // ---------------- phase B: 2-layer LSTM recurrence --------------------
    const int g = l;
    const float bias0 = bsum[g];
    const float bias1 = bi1[g] + bh1[g];
    float w0[16], w1[16], w2[16];
    #pragma unroll
    for (int q = 0; q < 4; ++q) {
        float4 v0 = *(const float4*)(whh0 + g * HH + q * 4);
        w0[q*4+0] = v0.x; w0[q*4+1] = v0.y; w0[q*4+2] = v0.z; w0[q*4+3] = v0.w;
        float4 v1 = *(const float4*)(wih1 + g * HH + q * 4);
        w1[q*4+0] = v1.x; w1[q*4+1] = v1.y; w1[q*4+2] = v1.z; w1[q*4+3] = v1.w;
        float4 v2 = *(const float4*)(whh1 + g * HH + q * 4);
        w2[q*4+0] = v2.x; w2[q*4+1] = v2.y; w2[q*4+2] = v2.z; w2[q*4+3] = v2.w;
    }
    const bool isg = (g & 48) == 32;
    const float m1 = isg ? 2.0f : 1.0f;   // unified sig/tanh
    const float b2 = isg ? -1.0f : 0.0f;

    // prefetch xg from LDS (static indices)
    float xv[2][TT];
    #pragma unroll
    for (int sm = 0; sm < 2; ++sm) {
        const int smp = wv * 2 + sm;
        #pragma unroll
        for (int t = 0; t < TT; ++t) {
            const int rl0 = smp * TT + t;          // 0..79
            const int T = rl0 >> 4, r = rl0 & 15;
            const int src = (((T * 4 + (g >> 4)) * 64 + ((r >> 2) << 4) + (g & 15)) << 2) + (r & 3);
            xv[sm][t] = (float)xg[src];
        }
    }

    float h0[2] = {0, 0}, c0[2] = {0, 0}, h1[2] = {0, 0}, c1[2] = {0, 0};
    #pragma unroll
    for (int t = 0; t < TT; ++t) {
        #pragma unroll
        for (int sm = 0; sm < 2; ++sm) {
            float s0 = xv[sm][t] + bias0, s1 = 0.0f, s2 = 0.0f, s3 = 0.0f;
            #pragma unroll
            for (int q = 0; q < 4; ++q) {
                s0 += rl_(h0[sm], 4*q + 0) * w0[4*q + 0];
                s1 += rl_(h0[sm], 4*q + 1) * w0[4*q + 1];
                s2 += rl_(h0[sm], 4*q + 2) * w0[4*q + 2];
                s3 += rl_(h0[sm], 4*q + 3) * w0[4*q + 3];
            }
            float z = ((s0 + s1) + (s2 + s3)) * m1;
            float a = m1 / (1.0f + __expf(-z)) + b2;
            float af = __shfl_down(a, 16, 64);
            float ac = __shfl_down(a, 32, 64);
            float ao = __shfl_down(a, 48, 64);
            c0[sm] = af * c0[sm] + a * ac;
            float e0 = __expf(2.0f * c0[sm]);
            h0[sm] = ao * (1.0f - 2.0f / (e0 + 1.0f));

            float u0 = bias1, u1 = 0.0f, u2 = 0.0f, u3 = 0.0f;
            float v0 = 0.0f, v1 = 0.0f, v2 = 0.0f, v3 = 0.0f;
            #pragma unroll
            for (int q = 0; q < 4; ++q) {
                u0 += rl_(h0[sm], 4*q + 0) * w1[4*q + 0];
                u1 += rl_(h0[sm], 4*q + 1) * w1[4*q + 1];
                u2 += rl_(h0[sm], 4*q + 2) * w1[4*q + 2];
                u3 += rl_(h0[sm], 4*q + 3) * w1[4*q + 3];
                v0 += rl_(h1[sm], 4*q + 0) * w2[4*q + 0];
                v1 += rl_(h1[sm], 4*q + 1) * w2[4*q + 1];
                v2 += rl_(h1[sm], 4*q + 2) * w2[4*q + 2];
                v3 += rl_(h1[sm], 4*q + 3) * w2[4*q + 3];
            }
            float z1 = (((u0 + v0) + (u1 + v1)) + ((u2 + v2) + (u3 + v3))) * m1;
            float a1 = m1 / (1.0f + __expf(-z1)) + b2;
            af = __shfl_down(a1, 16, 64);
            ac = __shfl_down(a1, 32, 64);
            ao = __shfl_down(a1, 48, 64);
            c1[sm] = af * c1[sm] + a1 * ac;
            float e1 = __expf(2.0f * c1[sm]);
            float h1v = ao * (1.0f - 2.0f / (e1 + 1.0f));
            h1[sm] = h1v;
            if (g < HH) ls2[wv * 2 + sm][t * HH + g] = h1v;
        }
    }
    __syncthreads();

    // ---------------- phase C: flat store + BN partials -------------------
    #pragma unroll
    for (int idx = 0; idx < 5; ++idx) {
        const int fi = tid + idx * 256;            // 0..1279 = 8*160
        const int s = fi / NF, j = fi - s * NF;
        flatH[(size_t)(blk * SPB + s) * NF + j] = (_Float16)ls2[s][j];
    }
    if (tid < NF) {
        float S = 0.0f, Q = 0.0f;
        #pragma unroll
        for (int s = 0; s < SPB; ++s) {
            float v = ls2[s][tid];
            S += v; Q += v * v;
        }
        psumT[(size_t)tid * NBLK + blk] = S;
        psqT[(size_t)tid * NBLK + blk] = Q;
    }
}

// K2: reduce 2048 block-partials per feature -> fused BN scale/shift.
__global__ __launch_bounds__(256) void k_bnB(
        const float* __restrict__ psumT, const float* __restrict__ psqT,
        const float* __restrict__ gamma, const float* __restrict__ beta,
        float* __restrict__ scale, float* __restrict__ shift) {
    const int f = blockIdx.x;
    const int tid = threadIdx.x;
    const float* ps = psumT + (size_t)f * NBLK;
    const float* pq = psqT + (size_t)f * NBLK;
    float s = 0.0f, q = 0.0f;
    for (int p = tid; p < NBLK; p += 256) { s += ps[p]; q += pq[p]; }
    #pragma unroll
    for (int o = 32; o > 0; o >>= 1) {
        s += __shfl_down(s, o, 64);
        q += __shfl_down(q, o, 64);
    }
    __shared__ float rs[4], rq[4];
    const int wv = tid >> 6;
    if ((tid & 63) == 0) { rs[wv] = s; rq[wv] = q; }
    __syncthreads();
    if (tid == 0) {
        float S = rs[0] + rs[1] + rs[2] + rs[3];
        float Q = rq[0] + rq[1] + rq[2] + rq[3];
        float mean = S * (1.0f / NB);
        float var = Q * (1.0f / NB) - mean * mean;
        float sc = gamma[f] * rsqrtf(var + 1e-5f);
        scale[f] = sc;
        shift[f] = beta[f] - mean * sc;
    }
}

// K3: BN-apply + LeakyReLU + concat + FC(162->2) + softmax (f16 flat).
__global__ __launch_bounds__(256) void k_fc(
        const _Float16* __restrict__ flatH, const float* __restrict__ scale,
        const float* __restrict__ shift, const float* __restrict__ ag,
        const float* __restrict__ fcw, const float* __restrict__ fcb,
        float* __restrict__ out) {
    const int lane = threadIdx.x & 63;
    const int b = blockIdx.x * 4 + (threadIdx.x >> 6);
    const _Float16* fr = flatH + (size_t)b * NF;
    float p0 = 0.0f, p1 = 0.0f;
    #pragma unroll
    for (int i = 0; i < 3; ++i) {
        const int f = lane + i * 64;
        if (f < NF) {
            float xn = (float)fr[f] * scale[f] + shift[f];
            float a = xn >= 0.0f ? xn : 0.01f * xn;
            p0 += a * fcw[f];
            p1 += a * fcw[162 + f];
        }
    }
    #pragma unroll
    for (int o = 32; o > 0; o >>= 1) {
        p0 += __shfl_down(p0, o, 64);
        p1 += __shfl_down(p1, o, 64);
    }
    if (lane == 0) {
        float a0 = ag[(size_t)b * 2 + 0], a1 = ag[(size_t)b * 2 + 1];
        float l0 = p0 + a0 * fcw[160] + a1 * fcw[161] + fcb[0];
        float l1 = p1 + a0 * fcw[162 + 160] + a1 * fcw[162 + 161] + fcb[1];
        float m = fmaxf(l0, l1);
        float e0 = __expf(l0 - m), e1 = __expf(l1 - m);
        float inv = 1.0f / (e0 + e1);
        out[(size_t)b * 2 + 0] = e0 * inv;
        out[(size_t)b * 2 + 1] = e1 * inv;
    }
}

extern "C" void kernel_launch(void* const* d_in, const int* in_sizes, int n_in,
                              void* d_out, int out_size, void* d_ws, size_t ws_size,
                              hipStream_t stream) {
    const float* x     = (const float*)d_in[0];
    const float* ag    = (const float*)d_in[1];
    const float* wih0  = (const float*)d_in[2];
    const float* whh0  = (const float*)d_in[3];
    const float* bih0  = (const float*)d_in[4];
    const float* bhh0  = (const float*)d_in[5];
    const float* wih1  = (const float*)d_in[6];
    const float* whh1  = (const float*)d_in[7];
    const float* bih1  = (const float*)d_in[8];
    const float* bhh1  = (const float*)d_in[9];
    const float* gamma = (const float*)d_in[10];
    const float* beta  = (const float*)d_in[11];
    const float* fcw   = (const float*)d_in[12];
    const float* fcb   = (const float*)d_in[13];
    float* out = (float*)d_out;

    float* ws = (float*)d_ws;
    _Float16* flatH = (_Float16*)ws;               // 2,621,440 halfs (1,310,720 slots)
    float* psumT = ws + 1310720;                   //   327,680 (160 x 2048)
    float* psqT  = ws + 1638400;                   //   327,680
    float* scale = ws + 1966080;                   //       160
    float* shift = ws + 1966240;                   //       160
    half8* Bf    = (half8*)(ws + 1966400);         //     8,192 f32-slots (32 KB)
    float* bsum  = ws + 1974592;                   //        64

    k_prep<<<dim3(8),     dim3(256), 0, stream>>>(wih0, bih0, bhh0, Bf, bsum);
    k_fused<<<dim3(NBLK), dim3(256), 0, stream>>>(x, Bf, bsum, whh0, wih1, whh1,
                                                  bih1, bhh1, flatH, psumT, psqT);
    k_bnB<<<dim3(160),   dim3(256), 0, stream>>>(psumT, psqT, gamma, beta, scale, shift);
    k_fc<<<dim3(4096),   dim3(256), 0, stream>>>(flatH, scale, shift, ag, fcw, fcb, out);
}

// Round 12
// 104.520 us; speedup vs baseline: 1.0489x; 1.0489x over previous
//
#include <hip/hip_runtime.h>

#define NB 16384
#define TT 10
#define DIN 256
#define HH 16
#define NG 64      // 4*H
#define NF 160     // T*H
#define NBLK 2048

typedef __attribute__((ext_vector_type(8))) _Float16 half8;
typedef __attribute__((ext_vector_type(4))) _Float16 half4;
typedef __attribute__((ext_vector_type(4))) float f32x4;

__device__ __forceinline__ float rl_(float v, int l) {
    return __int_as_float(__builtin_amdgcn_readlane(__float_as_int(v), l));
}

// K0: one-time prep. B fragments (fp16, lane order) + fused layer-0 bias.
// lane l holds B[col=c*16+(l&15)][k=s*32+(l>>4)*8+j], at Bf[(c*8+s)*64+l].
__global__ __launch_bounds__(256) void k_prep(
        const float* __restrict__ w, const float* __restrict__ bi,
        const float* __restrict__ bh, half8* __restrict__ Bf,
        float* __restrict__ bsum) {
    const int fi = blockIdx.x * 256 + threadIdx.x;   // 0..2047
    const int c = fi >> 9;
    const int s = (fi >> 6) & 7;
    const int ll = fi & 63;
    const int row = c * 16 + (ll & 15);
    const int k0 = s * 32 + ((ll >> 4) << 3);
    const float* wp = w + (size_t)row * DIN + k0;
    float4 a = *(const float4*)wp;
    float4 b = *(const float4*)(wp + 4);
    half8 h;
    h[0] = (_Float16)a.x; h[1] = (_Float16)a.y;
    h[2] = (_Float16)a.z; h[3] = (_Float16)a.w;
    h[4] = (_Float16)b.x; h[5] = (_Float16)b.y;
    h[6] = (_Float16)b.z; h[7] = (_Float16)b.w;
    Bf[fi] = h;
    if (blockIdx.x == 0 && threadIdx.x < NG)
        bsum[threadIdx.x] = bi[threadIdx.x] + bh[threadIdx.x];
}

// K1: xg = x.w^T + bias via f16 MFMA (hi/lo split).
// REGISTER-STREAMING version: zero LDS, zero barriers, zero asm waits.
// Wave owns one 16-row tile (16KB contiguous x). K in 4 chunks; chunk kc+1's
// A (4 dwordx4) and B (8 dwordx4, L2-resident Bf) loads issue BEFORE chunk
// kc's compute uses its registers -> compiler emits counted vmcnt, ~12KB
// in flight per wave through the whole tile. ~3 waves/SIMD (VGPR-bound),
// -> ~140KB/CU in flight (3-8x all prior attempts).
__global__ __launch_bounds__(256) void k_proj(
        const float* __restrict__ x, const half8* __restrict__ Bf,
        const float* __restrict__ bsum, _Float16* __restrict__ xgH) {
    const int l = threadIdx.x & 63;
    const int wid = (blockIdx.x * 256 + threadIdx.x) >> 6;   // tile id 0..10239
    const int rowA = wid * 16 + (l & 15);
    const int kb = (l >> 4) << 3;                            // 0,8,16,24
    const float* xr = x + (size_t)rowA * DIN + kb;

    // ---- load chunk 0 (A: s=0,1; B: c*2+sl fragments) ----
    f32x4 a0[4], a1[4];
    half8 b0[8], b1[8];
    #pragma unroll
    for (int sl = 0; sl < 2; ++sl) {
        a0[sl * 2 + 0] = *(const f32x4*)(xr + sl * 32);
        a0[sl * 2 + 1] = *(const f32x4*)(xr + sl * 32 + 4);
        #pragma unroll
        for (int c = 0; c < 4; ++c)
            b0[c * 2 + sl] = Bf[(c * 8 + sl) * 64 + l];
    }

    f32x4 acc[4];
    #pragma unroll
    for (int c = 0; c < 4; ++c) acc[c] = (f32x4)0.0f;

    #pragma unroll
    for (int kc = 0; kc < 4; ++kc) {
        const bool even = (kc & 1) == 0;
        f32x4* ac = even ? a0 : a1;
        half8* bc = even ? b0 : b1;
        f32x4* an = even ? a1 : a0;
        half8* bn = even ? b1 : b0;

        // issue next chunk's loads first (stay in flight during compute)
        if (kc < 3) {
            const int kn = (kc + 1) * 64;
            #pragma unroll
            for (int sl = 0; sl < 2; ++sl) {
                an[sl * 2 + 0] = *(const f32x4*)(xr + kn + sl * 32);
                an[sl * 2 + 1] = *(const f32x4*)(xr + kn + sl * 32 + 4);
                #pragma unroll
                for (int c = 0; c < 4; ++c)
                    bn[c * 2 + sl] = Bf[(c * 8 + (kc + 1) * 2 + sl) * 64 + l];
            }
        }

        // compute current chunk (2 slices x 4 col-tiles x hi/lo)
        #pragma unroll
        for (int sl = 0; sl < 2; ++sl) {
            const f32x4 va = ac[sl * 2 + 0];
            const f32x4 vb = ac[sl * 2 + 1];
            float fv[8] = {va.x, va.y, va.z, va.w, vb.x, vb.y, vb.z, vb.w};
            half8 ah, al;
            #pragma unroll
            for (int j = 0; j < 8; ++j) {
                _Float16 hi = (_Float16)fv[j];
                ah[j] = hi;
                al[j] = (_Float16)(fv[j] - (float)hi);
            }
            #pragma unroll
            for (int c = 0; c < 4; ++c) {
                acc[c] = __builtin_amdgcn_mfma_f32_16x16x32_f16(ah, bc[c * 2 + sl], acc[c], 0, 0, 0);
                acc[c] = __builtin_amdgcn_mfma_f32_16x16x32_f16(al, bc[c * 2 + sl], acc[c], 0, 0, 0);
            }
        }
    }

    // epilogue: bias + f16 pack + coalesced fragment-layout store (8B/lane)
    #pragma unroll
    for (int c = 0; c < 4; ++c) {
        const float bb = bsum[c * 16 + (l & 15)];
        half4 hv;
        hv[0] = (_Float16)(acc[c][0] + bb);
        hv[1] = (_Float16)(acc[c][1] + bb);
        hv[2] = (_Float16)(acc[c][2] + bb);
        hv[3] = (_Float16)(acc[c][3] + bb);
        *(half4*)(xgH + (size_t)wid * 1024 + c * 256 + l * 4) = hv;
    }
}

// K2: fused 2-layer LSTM recurrence + per-block BN partial sums.
// xg read (f16) from fragment layout, all 10 timesteps prefetched up front.
__global__ __launch_bounds__(256) void k_lstm(
        const _Float16* __restrict__ xgH, const float* __restrict__ whh0,
        const float* __restrict__ wih1, const float* __restrict__ whh1,
        const float* __restrict__ bi1, const float* __restrict__ bh1,
        _Float16* __restrict__ flatH, float* __restrict__ psumT,
        float* __restrict__ psqT) {
    __shared__ float ls[4][NF];   // per-wave h1 history for BN partials
    const int g = threadIdx.x & 63;
    const int wv = threadIdx.x >> 6;
    const int b = blockIdx.x * 4 + wv;

    float xv[TT];
    #pragma unroll
    for (int t = 0; t < TT; ++t) {
        const int row = b * TT + t;
        const int addr = ((row >> 4) << 10) + ((g >> 4) << 8) +
                         (((row >> 2) & 3) << 6) + ((g & 15) << 2) + (row & 3);
        xv[t] = (float)xgH[addr];
    }

    float w0[16], w1[16], w2[16];
    #pragma unroll
    for (int q = 0; q < 4; ++q) {
        float4 v0 = *(const float4*)(whh0 + g * HH + q * 4);
        w0[q*4+0] = v0.x; w0[q*4+1] = v0.y; w0[q*4+2] = v0.z; w0[q*4+3] = v0.w;
        float4 v1 = *(const float4*)(wih1 + g * HH + q * 4);
        w1[q*4+0] = v1.x; w1[q*4+1] = v1.y; w1[q*4+2] = v1.z; w1[q*4+3] = v1.w;
        float4 v2 = *(const float4*)(whh1 + g * HH + q * 4);
        w2[q*4+0] = v2.x; w2[q*4+1] = v2.y; w2[q*4+2] = v2.z; w2[q*4+3] = v2.w;
    }
    const float bias1 = bi1[g] + bh1[g];
    const bool isg = (g & 48) == 32;
    const float m1 = isg ? 2.0f : 1.0f;   // unified sig/tanh
    const float b2 = isg ? -1.0f : 0.0f;
    float h0 = 0.0f, c0 = 0.0f, h1 = 0.0f, c1 = 0.0f;

    #pragma unroll
    for (int t = 0; t < TT; ++t) {
        float s0 = xv[t], s1 = 0.0f, s2 = 0.0f, s3 = 0.0f;
        #pragma unroll
        for (int q = 0; q < 4; ++q) {
            s0 += rl_(h0, 4*q + 0) * w0[4*q + 0];
            s1 += rl_(h0, 4*q + 1) * w0[4*q + 1];
            s2 += rl_(h0, 4*q + 2) * w0[4*q + 2];
            s3 += rl_(h0, 4*q + 3) * w0[4*q + 3];
        }
        float z = ((s0 + s1) + (s2 + s3)) * m1;
        float a = m1 / (1.0f + __expf(-z)) + b2;
        float af = __shfl_down(a, 16, 64);
        float ac = __shfl_down(a, 32, 64);
        float ao = __shfl_down(a, 48, 64);
        c0 = af * c0 + a * ac;
        float e0 = __expf(2.0f * c0);
        h0 = ao * (1.0f - 2.0f / (e0 + 1.0f));

        float u0 = bias1, u1 = 0.0f, u2 = 0.0f, u3 = 0.0f;
        float v0 = 0.0f, v1 = 0.0f, v2 = 0.0f, v3 = 0.0f;
        #pragma unroll
        for (int q = 0; q < 4; ++q) {
            u0 += rl_(h0, 4*q + 0) * w1[4*q + 0];
            u1 += rl_(h0, 4*q + 1) * w1[4*q + 1];
            u2 += rl_(h0, 4*q + 2) * w1[4*q + 2];
            u3 += rl_(h0, 4*q + 3) * w1[4*q + 3];
            v0 += rl_(h1, 4*q + 0) * w2[4*q + 0];
            v1 += rl_(h1, 4*q + 1) * w2[4*q + 1];
            v2 += rl_(h1, 4*q + 2) * w2[4*q + 2];
            v3 += rl_(h1, 4*q + 3) * w2[4*q + 3];
        }
        float z1 = (((u0 + v0) + (u1 + v1)) + ((u2 + v2) + (u3 + v3))) * m1;
        float a1 = m1 / (1.0f + __expf(-z1)) + b2;
        af = __shfl_down(a1, 16, 64);
        ac = __shfl_down(a1, 32, 64);
        ao = __shfl_down(a1, 48, 64);
        c1 = af * c1 + a1 * ac;
        float e1 = __expf(2.0f * c1);
        h1 = ao * (1.0f - 2.0f / (e1 + 1.0f));

        if (g < HH) {
            flatH[(size_t)b * NF + t * HH + g] = (_Float16)h1;
            ls[wv][t * HH + g] = h1;
        }
    }

    // BN partials: block's 4 samples; transposed [f][4096] for coalesced bnB.
    __syncthreads();
    const int tid = threadIdx.x;
    if (tid < NF) {
        float a0 = ls[0][tid], a1 = ls[1][tid], a2 = ls[2][tid], a3 = ls[3][tid];
        psumT[(size_t)tid * 4096 + blockIdx.x] = (a0 + a1) + (a2 + a3);
        psqT[(size_t)tid * 4096 + blockIdx.x] =
            (a0 * a0 + a1 * a1) + (a2 * a2 + a3 * a3);
    }
}

// K3: reduce 4096 block-partials per feature -> fused BN scale/shift.
__global__ __launch_bounds__(256) void k_bnB(
        const float* __restrict__ psumT, const float* __restrict__ psqT,
        const float* __restrict__ gamma, const float* __restrict__ beta,
        float* __restrict__ scale, float* __restrict__ shift) {
    const int f = blockIdx.x;
    const int tid = threadIdx.x;
    const float* ps = psumT + (size_t)f * 4096;
    const float* pq = psqT + (size_t)f * 4096;
    float s = 0.0f, q = 0.0f;
    for (int p = tid; p < 4096; p += 256) { s += ps[p]; q += pq[p]; }
    #pragma unroll
    for (int o = 32; o > 0; o >>= 1) {
        s += __shfl_down(s, o, 64);
        q += __shfl_down(q, o, 64);
    }
    __shared__ float rs[4], rq[4];
    const int wv = tid >> 6;
    if ((tid & 63) == 0) { rs[wv] = s; rq[wv] = q; }
    __syncthreads();
    if (tid == 0) {
        float S = rs[0] + rs[1] + rs[2] + rs[3];
        float Q = rq[0] + rq[1] + rq[2] + rq[3];
        float mean = S * (1.0f / NB);
        float var = Q * (1.0f / NB) - mean * mean;
        float sc = gamma[f] * rsqrtf(var + 1e-5f);
        scale[f] = sc;
        shift[f] = beta[f] - mean * sc;
    }
}

// K4: BN-apply + LeakyReLU + concat + FC(162->2) + softmax (f16 flat).
__global__ __launch_bounds__(256) void k_fc(
        const _Float16* __restrict__ flatH, const float* __restrict__ scale,
        const float* __restrict__ shift, const float* __restrict__ ag,
        const float* __restrict__ fcw, const float* __restrict__ fcb,
        float* __restrict__ out) {
    const int lane = threadIdx.x & 63;
    const int b = blockIdx.x * 4 + (threadIdx.x >> 6);
    const _Float16* fr = flatH + (size_t)b * NF;
    float p0 = 0.0f, p1 = 0.0f;
    #pragma unroll
    for (int i = 0; i < 3; ++i) {
        const int f = lane + i * 64;
        if (f < NF) {
            float xn = (float)fr[f] * scale[f] + shift[f];
            float a = xn >= 0.0f ? xn : 0.01f * xn;
            p0 += a * fcw[f];
            p1 += a * fcw[162 + f];
        }
    }
    #pragma unroll
    for (int o = 32; o > 0; o >>= 1) {
        p0 += __shfl_down(p0, o, 64);
        p1 += __shfl_down(p1, o, 64);
    }
    if (lane == 0) {
        float a0 = ag[(size_t)b * 2 + 0], a1 = ag[(size_t)b * 2 + 1];
        float l0 = p0 + a0 * fcw[160] + a1 * fcw[161] + fcb[0];
        float l1 = p1 + a0 * fcw[162 + 160] + a1 * fcw[162 + 161] + fcb[1];
        float m = fmaxf(l0, l1);
        float e0 = __expf(l0 - m), e1 = __expf(l1 - m);
        float inv = 1.0f / (e0 + e1);
        out[(size_t)b * 2 + 0] = e0 * inv;
        out[(size_t)b * 2 + 1] = e1 * inv;
    }
}

extern "C" void kernel_launch(void* const* d_in, const int* in_sizes, int n_in,
                              void* d_out, int out_size, void* d_ws, size_t ws_size,
                              hipStream_t stream) {
    const float* x     = (const float*)d_in[0];
    const float* ag    = (const float*)d_in[1];
    const float* wih0  = (const float*)d_in[2];
    const float* whh0  = (const float*)d_in[3];
    const float* bih0  = (const float*)d_in[4];
    const float* bhh0  = (const float*)d_in[5];
    const float* wih1  = (const float*)d_in[6];
    const float* whh1  = (const float*)d_in[7];
    const float* bih1  = (const float*)d_in[8];
    const float* bhh1  = (const float*)d_in[9];
    const float* gamma = (const float*)d_in[10];
    const float* beta  = (const float*)d_in[11];
    const float* fcw   = (const float*)d_in[12];
    const float* fcb   = (const float*)d_in[13];
    float* out = (float*)d_out;

    float* ws = (float*)d_ws;
    _Float16* xgH   = (_Float16*)ws;               // 10,485,760 halfs
    _Float16* flatH = (_Float16*)(ws + 5242880);   //  2,621,440 halfs
    float* psumT = ws + 6553600;                   //    655,360 (160 x 4096)
    float* psqT  = ws + 7208960;                   //    655,360
    float* scale = ws + 7864320;                   //        160
    float* shift = ws + 7864480;                   //        160
    half8* Bf    = (half8*)(ws + 7864640);         //      8,192 f32-slots (32 KB)
    float* bsum  = ws + 7872832;                   //         64

    k_prep<<<dim3(8),    dim3(256), 0, stream>>>(wih0, bih0, bhh0, Bf, bsum);
    k_proj<<<dim3(2560), dim3(256), 0, stream>>>(x, Bf, bsum, xgH);
    k_lstm<<<dim3(4096), dim3(256), 0, stream>>>(xgH, whh0, wih1, whh1, bih1, bhh1,
                                                 flatH, psumT, psqT);
    k_bnB<<<dim3(160),  dim3(256), 0, stream>>>(psumT, psqT, gamma, beta, scale, shift);
    k_fc<<<dim3(4096),  dim3(256), 0, stream>>>(flatH, scale, shift, ag, fcw, fcb, out);
}

// Round 14
// 56.806 us; speedup vs baseline: 1.9300x; 1.8400x over previous
//
#include <hip/hip_runtime.h>

#define NB 16384
#define TT 10
#define DIN 256
#define HH 16
#define NG 64      // 4*H
#define NF 160     // T*H

typedef __attribute__((ext_vector_type(8))) _Float16 half8;
typedef __attribute__((ext_vector_type(4))) _Float16 half4;
typedef __attribute__((ext_vector_type(4))) float f32x4;
typedef unsigned int u32;

__device__ __forceinline__ void gld16(const float* g, float* l) {
    __builtin_amdgcn_global_load_lds(
        (const __attribute__((address_space(1))) u32*)g,
        (__attribute__((address_space(3))) u32*)l, 16, 0, 0);
}
__device__ __forceinline__ float sigf(float x) { return 1.0f / (1.0f + __expf(-x)); }
__device__ __forceinline__ float tanhf_(float x) {
    float e = __expf(2.0f * x);
    return 1.0f - 2.0f / (e + 1.0f);
}

// K0: prep. (a) Wih0 fragments fp16 lane order (validated convention):
// Bf[(c*8+s)*64+l] = W[gate=c*16+(l&15)][k=s*32+(l>>4)*8+j].  (b) recurrence
// A-fragments for 16x16x16: recw[m][c*64+l] = M[c*16+(l&15)][(l>>4)*4+j].
// (c) fused biases.
__global__ __launch_bounds__(256) void k_prep(
        const float* __restrict__ w, const float* __restrict__ bi,
        const float* __restrict__ bh, const float* __restrict__ whh0,
        const float* __restrict__ wih1, const float* __restrict__ whh1,
        const float* __restrict__ bi1, const float* __restrict__ bh1,
        half8* __restrict__ Bf, float* __restrict__ bsum,
        half4* __restrict__ recw, float* __restrict__ b1s) {
    const int fi = blockIdx.x * 256 + threadIdx.x;   // 0..2047
    {
        const int c = fi >> 9;
        const int s = (fi >> 6) & 7;
        const int ll = fi & 63;
        const int row = c * 16 + (ll & 15);
        const int k0 = s * 32 + ((ll >> 4) << 3);
        const float* wp = w + (size_t)row * DIN + k0;
        float4 a = *(const float4*)wp;
        float4 b = *(const float4*)(wp + 4);
        half8 h;
        h[0] = (_Float16)a.x; h[1] = (_Float16)a.y;
        h[2] = (_Float16)a.z; h[3] = (_Float16)a.w;
        h[4] = (_Float16)b.x; h[5] = (_Float16)b.y;
        h[6] = (_Float16)b.z; h[7] = (_Float16)b.w;
        Bf[fi] = h;
    }
    if (blockIdx.x < 3) {
        const float* M = blockIdx.x == 0 ? whh0 : (blockIdx.x == 1 ? wih1 : whh1);
        const int c = threadIdx.x >> 6;
        const int ll = threadIdx.x & 63;
        float4 v = *(const float4*)(M + (size_t)(c * 16 + (ll & 15)) * HH + ((ll >> 4) << 2));
        half4 h4;
        h4[0] = (_Float16)v.x; h4[1] = (_Float16)v.y;
        h4[2] = (_Float16)v.z; h4[3] = (_Float16)v.w;
        recw[blockIdx.x * 256 + c * 64 + ll] = h4;
    }
    if (blockIdx.x == 3 && threadIdx.x < NG) {
        bsum[threadIdx.x] = bi[threadIdx.x] + bh[threadIdx.x];
        b1s[threadIdx.x] = bi1[threadIdx.x] + bh1[threadIdx.x];
    }
}

// K1: MEGAFUSED proj + 2-layer LSTM. One wave = 16 samples (sb).
// Orientation: C[gate][sample] (A=W, B=x/h; col=sample=l&15).
// Recurrence h feeds back as B-operand with IDENTITY layout (C row formula
// == B k formula for 16x16x16). No xg materialization, no shuffles, no
// inter-wave communication; Bl is read-only after one barrier.
__global__ __launch_bounds__(256, 1) void k_mega(
        const float* __restrict__ x, const half8* __restrict__ Bf,
        const float* __restrict__ bsum, const half4* __restrict__ recw,
        const float* __restrict__ b1s, _Float16* __restrict__ flatT) {
    __shared__ half8 Bl[2048];   // 32 KB Wih0 fragments
    const int tid = threadIdx.x;
    const int l = tid & 63;
    const int wv = tid >> 6;

    #pragma unroll
    for (int q = 0; q < 8; ++q)
        gld16((const float*)(Bf + (wv * 8 + q) * 64 + l),
              (float*)(Bl + (wv * 8 + q) * 64));

    half4 w0f[4], w1f[4], w2f[4];
    f32x4 b0[4], b1[4];
    #pragma unroll
    for (int c = 0; c < 4; ++c) {
        w0f[c] = recw[0 * 256 + c * 64 + l];
        w1f[c] = recw[1 * 256 + c * 64 + l];
        w2f[c] = recw[2 * 256 + c * 64 + l];
        b0[c] = *(const f32x4*)(bsum + c * 16 + ((l >> 4) << 2));
        b1[c] = *(const f32x4*)(b1s + c * 16 + ((l >> 4) << 2));
    }
    __syncthreads();   // Bl staged (vmcnt drained by barrier semantics)

    const int sb = blockIdx.x * 4 + wv;              // sample-block 0..1023
    const float* xp = x + (size_t)(sb * 16 + (l & 15)) * TT * DIN + ((l >> 4) << 3);

    f32x4 A0[8], B0[8], A1[8], B1[8];
    #pragma unroll
    for (int s = 0; s < 8; ++s) {
        A0[s] = *(const f32x4*)(xp + s * 32);
        B0[s] = *(const f32x4*)(xp + s * 32 + 4);
    }

    half4 h0f, h1f;
    #pragma unroll
    for (int j = 0; j < 4; ++j) { h0f[j] = (_Float16)0.0f; h1f[j] = (_Float16)0.0f; }
    f32x4 cs0 = (f32x4)0.0f, cs1 = (f32x4)0.0f;

#define STEP(t, CA, CB, NA, NB2)                                               \
    {                                                                          \
        if ((t) < 9) {                                                         \
            _Pragma("unroll")                                                  \
            for (int s = 0; s < 8; ++s) {                                      \
                NA[s] = *(const f32x4*)(xp + ((t) + 1) * DIN + s * 32);        \
                NB2[s] = *(const f32x4*)(xp + ((t) + 1) * DIN + s * 32 + 4);   \
            }                                                                  \
        }                                                                      \
        f32x4 ac0[4] = {b0[0], b0[1], b0[2], b0[3]};                           \
        _Pragma("unroll")                                                      \
        for (int s = 0; s < 8; ++s) {                                          \
            float fv[8] = {CA[s].x, CA[s].y, CA[s].z, CA[s].w,                 \
                           CB[s].x, CB[s].y, CB[s].z, CB[s].w};                \
            half8 xh, xl;                                                      \
            _Pragma("unroll")                                                  \
            for (int j = 0; j < 8; ++j) {                                      \
                _Float16 hi = (_Float16)fv[j];                                 \
                xh[j] = hi;                                                    \
                xl[j] = (_Float16)(fv[j] - (float)hi);                         \
            }                                                                  \
            _Pragma("unroll")                                                  \
            for (int c = 0; c < 4; ++c) {                                      \
                half8 wf = Bl[(c * 8 + s) * 64 + l];                           \
                ac0[c] = __builtin_amdgcn_mfma_f32_16x16x32_f16(wf, xh, ac0[c], 0, 0, 0); \
                ac0[c] = __builtin_amdgcn_mfma_f32_16x16x32_f16(wf, xl, ac0[c], 0, 0, 0); \
            }                                                                  \
        }                                                                      \
        _Pragma("unroll")                                                      \
        for (int c = 0; c < 4; ++c)                                            \
            ac0[c] = __builtin_amdgcn_mfma_f32_16x16x16f16(w0f[c], h0f, ac0[c], 0, 0, 0); \
        f32x4 h0v;                                                             \
        _Pragma("unroll")                                                      \
        for (int r = 0; r < 4; ++r) {                                          \
            float iv = sigf(ac0[0][r]), fg = sigf(ac0[1][r]);                  \
            float gv = tanhf_(ac0[2][r]), ov = sigf(ac0[3][r]);                \
            cs0[r] = fg * cs0[r] + iv * gv;                                    \
            h0v[r] = ov * tanhf_(cs0[r]);                                      \
        }                                                                      \
        h0f[0] = (_Float16)h0v[0]; h0f[1] = (_Float16)h0v[1];                  \
        h0f[2] = (_Float16)h0v[2]; h0f[3] = (_Float16)h0v[3];                  \
        f32x4 ac1[4] = {b1[0], b1[1], b1[2], b1[3]};                           \
        _Pragma("unroll")                                                      \
        for (int c = 0; c < 4; ++c) {                                          \
            ac1[c] = __builtin_amdgcn_mfma_f32_16x16x16f16(w1f[c], h0f, ac1[c], 0, 0, 0); \
            ac1[c] = __builtin_amdgcn_mfma_f32_16x16x16f16(w2f[c], h1f, ac1[c], 0, 0, 0); \
        }                                                                      \
        f32x4 h1v;                                                             \
        _Pragma("unroll")                                                      \
        for (int r = 0; r < 4; ++r) {                                          \
            float iv = sigf(ac1[0][r]), fg = sigf(ac1[1][r]);                  \
            float gv = tanhf_(ac1[2][r]), ov = sigf(ac1[3][r]);                \
            cs1[r] = fg * cs1[r] + iv * gv;                                    \
            h1v[r] = ov * tanhf_(cs1[r]);                                      \
        }                                                                      \
        h1f[0] = (_Float16)h1v[0]; h1f[1] = (_Float16)h1v[1];                  \
        h1f[2] = (_Float16)h1v[2]; h1f[3] = (_Float16)h1v[3];                  \
        _Pragma("unroll")                                                      \
        for (int r = 0; r < 4; ++r)                                            \
            flatT[(size_t)((t) * 16 + ((l >> 4) << 2) + r) * NB + sb * 16 + (l & 15)] = (_Float16)h1v[r]; \
    }

    STEP(0, A0, B0, A1, B1)
    STEP(1, A1, B1, A0, B0)
    STEP(2, A0, B0, A1, B1)
    STEP(3, A1, B1, A0, B0)
    STEP(4, A0, B0, A1, B1)
    STEP(5, A1, B1, A0, B0)
    STEP(6, A0, B0, A1, B1)
    STEP(7, A1, B1, A0, B0)
    STEP(8, A0, B0, A1, B1)
    STEP(9, A1, B1, A0, B0)
#undef STEP
}

// K2: BN stats directly from column-major flatT (fully coalesced).
__global__ __launch_bounds__(256) void k_bn(
        const _Float16* __restrict__ flatT, const float* __restrict__ gamma,
        const float* __restrict__ beta, float* __restrict__ scale,
        float* __restrict__ shift) {
    const int f = blockIdx.x;
    const int tid = threadIdx.x;
    const _Float16* col = flatT + (size_t)f * NB;
    float s = 0.0f, q = 0.0f;
    #pragma unroll 8
    for (int i = tid; i < NB; i += 256) {
        float v = (float)col[i];
        s += v; q += v * v;
    }
    #pragma unroll
    for (int o = 32; o > 0; o >>= 1) {
        s += __shfl_down(s, o, 64);
        q += __shfl_down(q, o, 64);
    }
    __shared__ float rs[4], rq[4];
    const int wv = tid >> 6;
    if ((tid & 63) == 0) { rs[wv] = s; rq[wv] = q; }
    __syncthreads();
    if (tid == 0) {
        float S = rs[0] + rs[1] + rs[2] + rs[3];
        float Q = rq[0] + rq[1] + rq[2] + rq[3];
        float mean = S * (1.0f / NB);
        float var = Q * (1.0f / NB) - mean * mean;
        float sc = gamma[f] * rsqrtf(var + 1e-5f);
        scale[f] = sc;
        shift[f] = beta[f] - mean * sc;
    }
}

// K3: BN-apply + LeakyReLU + concat + FC(162->2) + softmax.
// One THREAD per sample; flatT reads coalesced; weights via scalar loads.
__global__ __launch_bounds__(256) void k_fc(
        const _Float16* __restrict__ flatT, const float* __restrict__ scale,
        const float* __restrict__ shift, const float* __restrict__ ag,
        const float* __restrict__ fcw, const float* __restrict__ fcb,
        float* __restrict__ out) {
    const int smp = blockIdx.x * 256 + threadIdx.x;
    float p0 = 0.0f, p1 = 0.0f;
    #pragma unroll 8
    for (int f = 0; f < NF; ++f) {
        float xn = (float)flatT[(size_t)f * NB + smp] * scale[f] + shift[f];
        float a = xn >= 0.0f ? xn : 0.01f * xn;
        p0 += a * fcw[f];
        p1 += a * fcw[162 + f];
    }
    float a0 = ag[(size_t)smp * 2 + 0], a1 = ag[(size_t)smp * 2 + 1];
    float l0 = p0 + a0 * fcw[160] + a1 * fcw[161] + fcb[0];
    float l1 = p1 + a0 * fcw[162 + 160] + a1 * fcw[162 + 161] + fcb[1];
    float m = fmaxf(l0, l1);
    float e0 = __expf(l0 - m), e1 = __expf(l1 - m);
    float inv = 1.0f / (e0 + e1);
    out[(size_t)smp * 2 + 0] = e0 * inv;
    out[(size_t)smp * 2 + 1] = e1 * inv;
}

extern "C" void kernel_launch(void* const* d_in, const int* in_sizes, int n_in,
                              void* d_out, int out_size, void* d_ws, size_t ws_size,
                              hipStream_t stream) {
    const float* x     = (const float*)d_in[0];
    const float* ag    = (const float*)d_in[1];
    const float* wih0  = (const float*)d_in[2];
    const float* whh0  = (const float*)d_in[3];
    const float* bih0  = (const float*)d_in[4];
    const float* bhh0  = (const float*)d_in[5];
    const float* wih1  = (const float*)d_in[6];
    const float* whh1  = (const float*)d_in[7];
    const float* bih1  = (const float*)d_in[8];
    const float* bhh1  = (const float*)d_in[9];
    const float* gamma = (const float*)d_in[10];
    const float* beta  = (const float*)d_in[11];
    const float* fcw   = (const float*)d_in[12];
    const float* fcb   = (const float*)d_in[13];
    float* out = (float*)d_out;

    float* ws = (float*)d_ws;
    _Float16* flatT = (_Float16*)ws;           // 160 x 16384 halfs = 1,310,720 slots
    half8* Bf    = (half8*)(ws + 1310720);     // 8,192 slots (32 KB)
    half4* recw  = (half4*)(ws + 1318912);     // 3*256 half4 = 1,536 slots
    float* bsum  = ws + 1320448;               // 64
    float* b1s   = ws + 1320512;               // 64
    float* scale = ws + 1320576;               // 160
    float* shift = ws + 1320736;               // 160

    k_prep<<<dim3(8),   dim3(256), 0, stream>>>(wih0, bih0, bhh0, whh0, wih1, whh1,
                                                bih1, bhh1, Bf, bsum, recw, b1s);
    k_mega<<<dim3(256), dim3(256), 0, stream>>>(x, Bf, bsum, recw, b1s, flatT);
    k_bn<<<dim3(NF),    dim3(256), 0, stream>>>(flatT, gamma, beta, scale, shift);
    k_fc<<<dim3(64),    dim3(256), 0, stream>>>(flatT, scale, shift, ag, fcw, fcb, out);
}